// Round 8
// baseline (210.970 us; speedup 1.0000x reference)
//
#include <hip/hip_runtime.h>
#include <hip/hip_bf16.h>

#define N_TAGS 128
#define T_LEN  256
#define BSZ    256
#define ROOT_T 126
#define END_T  127

typedef _Float16 h2 __attribute__((ext_vector_type(2)));
typedef _Float16 h8 __attribute__((ext_vector_type(8)));
typedef int   i32x4 __attribute__((ext_vector_type(4)));

static __device__ __forceinline__ h2 pkrtz(float a, float b) {
  return __builtin_bit_cast(h2, __builtin_amdgcn_cvt_pkrtz(a, b));
}
static __device__ __forceinline__ float rfl(float x) {
  return __int_as_float(__builtin_amdgcn_readfirstlane(__float_as_int(x)));
}
static __device__ __forceinline__ float fdot2(h2 a, h2 b, float c) {
#if __has_builtin(__builtin_amdgcn_fdot2)
  return __builtin_amdgcn_fdot2(a, b, c, false);
#else
  float d;
  asm("v_dot2_f32_f16 %0, %1, %2, %3" : "=v"(d) : "v"(a), "v"(b), "v"(c));
  return d;
#endif
}
static __device__ __forceinline__ float wave_max(float x) {
  #pragma unroll
  for (int d = 1; d < 64; d <<= 1) x = fmaxf(x, __shfl_xor(x, d));
  return x;
}

// 128-length dual dot: s0 = sum_k p[k]*EA[k], s1 = sum_k p[k]*EB[k].
// p read from LDS as 16 wave-uniform b128 broadcasts (64 h2), f32 accumulate.
static __device__ __forceinline__ void dot128(const h2* __restrict__ psv,
                                              const h2 (&EA)[64], const h2 (&EB)[64],
                                              float& s0, float& s1) {
  const h8* pv = (const h8*)psv;
  float a0=0.f,a1=0.f,a2=0.f,a3=0.f, b0=0.f,b1=0.f,b2=0.f,b3=0.f;
  #pragma unroll
  for (int r = 0; r < 16; ++r) {
    const h8 v = pv[r];
    const h2 p0 = __builtin_shufflevector(v, v, 0, 1);
    const h2 p1 = __builtin_shufflevector(v, v, 2, 3);
    const h2 p2 = __builtin_shufflevector(v, v, 4, 5);
    const h2 p3 = __builtin_shufflevector(v, v, 6, 7);
    a0 = fdot2(p0, EA[4*r+0], a0);  a1 = fdot2(p1, EA[4*r+1], a1);
    a2 = fdot2(p2, EA[4*r+2], a2);  a3 = fdot2(p3, EA[4*r+3], a3);
    b0 = fdot2(p0, EB[4*r+0], b0);  b1 = fdot2(p1, EB[4*r+1], b1);
    b2 = fdot2(p2, EB[4*r+2], b2);  b3 = fdot2(p3, EB[4*r+3], b3);
  }
  s0 = (a0 + a1) + (a2 + a3);
  s1 = (b0 + b1) + (b2 + b3);
}

// One block per TWO batches (b0=2*bid, b1=2*bid+1). 128 threads = 2 waves.
// Wave 0: forward recurrences of BOTH chains; wave 1: backward of both.
// The E=exp(lt) registers are shared by both chains (batch-invariant), so the
// second chain costs only ~24 extra VGPRs but its independent dep-chain fills
// the ~74% stall fraction measured in round 7 (VALUBusy 26%).
// No barrier in the main loops (per-wave LDS round-trips, in-order DS).
__global__ void
__attribute__((amdgpu_flat_work_group_size(128, 128), amdgpu_waves_per_eu(1, 1)))
crf_fwd_kernel(
    const float* __restrict__ feats,   // [BSZ][T_LEN][N_TAGS]
    const int*   __restrict__ tags,    // [BSZ][T_LEN]
    const int*   __restrict__ mask,    // [BSZ][T_LEN]
    const float* __restrict__ lt,      // [N_TAGS][N_TAGS]
    float*       __restrict__ per_batch)
{
  const int b0   = 2 * blockIdx.x;
  const int b1   = b0 + 1;
  const int tid  = threadIdx.x;
  const int lane = tid & 63;
  const int wave = tid >> 6;

  __shared__ __align__(16) h2 psF[2][2][64];   // [chain][buf][64]
  __shared__ __align__(16) h2 psB[2][2][64];
  __shared__ float stage[32 * 129];
  __shared__ float bbs[2][N_TAGS];             // beta_128 per chain
  __shared__ float sred[2][2];                 // [chain][wave]

  const float* fb0 = feats + (size_t)b0 * T_LEN * N_TAGS;
  const float* fb1 = feats + (size_t)b1 * T_LEN * N_TAGS;
  const int*   tb0 = tags + b0 * T_LEN;
  const int*   tb1 = tags + b1 * T_LEN;

  // ---- sequence lengths (prefix masks), per-wave independent ----
  int lenA, lenB;
  {
    const i32x4 mvA = ((const i32x4*)(mask + b0 * T_LEN))[lane];
    const i32x4 mvB = ((const i32x4*)(mask + b1 * T_LEN))[lane];
    int vA = mvA.x + mvA.y + mvA.z + mvA.w;
    int vB = mvB.x + mvB.y + mvB.z + mvB.w;
    #pragma unroll
    for (int d = 1; d < 64; d <<= 1) { vA += __shfl_xor(vA, d); vB += __shfl_xor(vB, d); }
    lenA = __builtin_amdgcn_readfirstlane(vA);
    lenB = __builtin_amdgcn_readfirstlane(vB);
  }

  // ---- f16 register-resident E = exp(lt), shared by both chains ----
  // wave0 lane l: EA[q]={E[2q][2l],E[2q+1][2l]}, EB for col 2l+1 (row-pairs).
  // wave1 lane l: EA[q]={E[2l][2q],E[2l][2q+1]}, EB for row 2l+1 (col-pairs).
  h2 EA[64], EB[64];
  #pragma unroll
  for (int c = 0; c < 4; ++c) {
    __syncthreads();
    #pragma unroll
    for (int rr = 0; rr < 32; ++rr)
      stage[rr * 129 + tid] = __expf(lt[(c * 32 + rr) * N_TAGS + tid]);
    __syncthreads();
    if (wave == 0) {
      #pragma unroll
      for (int k = 0; k < 16; ++k) {
        h2 ea, eb;
        ea.x = (_Float16)stage[(2*k)   * 129 + 2*lane];
        ea.y = (_Float16)stage[(2*k+1) * 129 + 2*lane];
        eb.x = (_Float16)stage[(2*k)   * 129 + 2*lane + 1];
        eb.y = (_Float16)stage[(2*k+1) * 129 + 2*lane + 1];
        EA[c*16 + k] = ea;
        EB[c*16 + k] = eb;
      }
    } else if ((lane >> 4) == c) {
      const int r0 = 2 * lane - 32 * c;
      #pragma unroll
      for (int q = 0; q < 64; ++q) {
        h2 ea, eb;
        ea.x = (_Float16)stage[r0       * 129 + 2*q];
        ea.y = (_Float16)stage[r0       * 129 + 2*q + 1];
        eb.x = (_Float16)stage[(r0 + 1) * 129 + 2*q];
        eb.y = (_Float16)stage[(r0 + 1) * 129 + 2*q + 1];
        EA[q] = ea;
        EB[q] = eb;
      }
    }
  }

  float sA0, sA1, sB0, sB1;      // chain A / chain B states (2 tags per lane)

  if (wave == 0) {
    // ===== FORWARD both chains: steps t=1..128 (active iff t<len) =====
    {
      const float2 fA = ((const float2*)fb0)[lane];
      const float2 fB = ((const float2*)fb1)[lane];
      const float r0 = lt[ROOT_T * N_TAGS + 2*lane];
      const float r1 = lt[ROOT_T * N_TAGS + 2*lane + 1];
      sA0 = r0 + fA.x;  sA1 = r1 + fA.y;
      sB0 = r0 + fB.x;  sB1 = r1 + fB.y;
    }
    float2 faA = ((const float2*)(fb0 + 1 * N_TAGS))[lane];
    float2 fcA = ((const float2*)(fb0 + 2 * N_TAGS))[lane];
    float2 faB = ((const float2*)(fb1 + 1 * N_TAGS))[lane];
    float2 fcB = ((const float2*)(fb1 + 2 * N_TAGS))[lane];
    float mA = rfl(sA0) + 2.0f;
    float mB = rfl(sB0) + 2.0f;
    psF[0][1][lane] = pkrtz(__expf(sA0 - mA), __expf(sA1 - mA));
    psF[1][1][lane] = pkrtz(__expf(sB0 - mB), __expf(sB1 - mB));

    #pragma unroll 1
    for (int k2 = 0; k2 < 64; ++k2) {
      #pragma unroll
      for (int h = 0; h < 2; ++h) {
        const int t  = 2 * k2 + 1 + h;
        const int rb = 1 - h, wb = h;
        float d0A, d1A, d0B, d1B;
        dot128(psF[0][rb], EA, EB, d0A, d1A);
        dot128(psF[1][rb], EA, EB, d0B, d1B);
        {
          const float nf0 = mA + __logf(d0A) + faA.x;
          const float nf1 = mA + __logf(d1A) + faA.y;
          const bool act = (t < lenA);
          sA0 = act ? nf0 : sA0;  sA1 = act ? nf1 : sA1;
          faA = fcA;
          fcA = ((const float2*)(fb0 + (t + 2) * N_TAGS))[lane];
          const float m = rfl(sA0) + 2.0f;
          psF[0][wb][lane] = pkrtz(__expf(sA0 - m), __expf(sA1 - m));
          mA = m;
        }
        {
          const float nf0 = mB + __logf(d0B) + faB.x;
          const float nf1 = mB + __logf(d1B) + faB.y;
          const bool act = (t < lenB);
          sB0 = act ? nf0 : sB0;  sB1 = act ? nf1 : sB1;
          faB = fcB;
          fcB = ((const float2*)(fb1 + (t + 2) * N_TAGS))[lane];
          const float m = rfl(sB0) + 2.0f;
          psF[1][wb][lane] = pkrtz(__expf(sB0 - m), __expf(sB1 - m));
          mB = m;
        }
      }
    }
    // sA,sB = alpha_128 of chains A,B
  } else {
    // ===== BACKWARD both chains: step k uses f[255-k];
    //       active iff 256-len <= k <= 126; ends at beta_128 =====
    {
      const float e0 = lt[(2*lane)     * N_TAGS + END_T];
      const float e1 = lt[(2*lane + 1) * N_TAGS + END_T];
      sA0 = e0;  sA1 = e1;
      sB0 = e0;  sB1 = e1;
    }
    float2 fwA = ((const float2*)(fb0 + 255 * N_TAGS))[lane];
    float2 faA = ((const float2*)(fb0 + 254 * N_TAGS))[lane];
    float2 fcA = ((const float2*)(fb0 + 253 * N_TAGS))[lane];
    float2 fwB = ((const float2*)(fb1 + 255 * N_TAGS))[lane];
    float2 faB = ((const float2*)(fb1 + 254 * N_TAGS))[lane];
    float2 fcB = ((const float2*)(fb1 + 253 * N_TAGS))[lane];
    const float yA0i = sA0 + fwA.x, yA1i = sA1 + fwA.y;
    const float yB0i = sB0 + fwB.x, yB1i = sB1 + fwB.y;
    float mA = rfl(yA0i) + 2.0f;
    float mB = rfl(yB0i) + 2.0f;
    psB[0][1][lane] = pkrtz(__expf(yA0i - mA), __expf(yA1i - mA));
    psB[1][1][lane] = pkrtz(__expf(yB0i - mB), __expf(yB1i - mB));

    const int kminA = 256 - lenA;
    const int kminB = 256 - lenB;
    #pragma unroll 1
    for (int k2 = 0; k2 < 64; ++k2) {
      #pragma unroll
      for (int h = 0; h < 2; ++h) {
        const int k  = 2 * k2 + h;
        const int rb = 1 - h, wb = h;
        float d0A, d1A, d0B, d1B;
        dot128(psB[0][rb], EA, EB, d0A, d1A);
        dot128(psB[1][rb], EA, EB, d0B, d1B);
        {
          const float nb0 = mA + __logf(d0A);
          const float nb1 = mA + __logf(d1A);
          const bool act = (k >= kminA) && (k <= 126);
          sA0 = act ? nb0 : sA0;  sA1 = act ? nb1 : sA1;
          const float w0 = faA.x, w1 = faA.y;      // f[254-k]
          faA = fcA;
          fcA = ((const float2*)(fb0 + (252 - k) * N_TAGS))[lane];
          const float y0 = sA0 + w0, y1 = sA1 + w1;
          const float m = rfl(y0) + 2.0f;
          psB[0][wb][lane] = pkrtz(__expf(y0 - m), __expf(y1 - m));
          mA = m;
        }
        {
          const float nb0 = mB + __logf(d0B);
          const float nb1 = mB + __logf(d1B);
          const bool act = (k >= kminB) && (k <= 126);
          sB0 = act ? nb0 : sB0;  sB1 = act ? nb1 : sB1;
          const float w0 = faB.x, w1 = faB.y;
          faB = fcB;
          fcB = ((const float2*)(fb1 + (252 - k) * N_TAGS))[lane];
          const float y0 = sB0 + w0, y1 = sB1 + w1;
          const float m = rfl(y0) + 2.0f;
          psB[1][wb][lane] = pkrtz(__expf(y0 - m), __expf(y1 - m));
          mB = m;
        }
      }
    }
    // sA,sB = beta_128
    bbs[0][2*lane] = sA0;  bbs[0][2*lane + 1] = sA1;
    bbs[1][2*lane] = sB0;  bbs[1][2*lane + 1] = sB1;
  }
  __syncthreads();

  // ---- gold-path scores: 2 timesteps per thread per chain ----
  float cA = 0.f, cB = 0.f;
  #pragma unroll
  for (int q = 0; q < 2; ++q) {
    const int t = tid + q * N_TAGS;
    {
      const int tg = tb0[t];
      if (t == 0)                           cA += lt[ROOT_T * N_TAGS + tg];
      if (t >= 1 && t < lenA)               cA += lt[tb0[t - 1] * N_TAGS + tg];
      if (t < lenA && t <= T_LEN - 2)       cA += fb0[t * N_TAGS + tg];
      if (t == lenA - 1)                    cA += lt[tg * N_TAGS + END_T];
      if (t == T_LEN - 1 && lenA == T_LEN)  cA += fb0[t * N_TAGS + tg];
    }
    {
      const int tg = tb1[t];
      if (t == 0)                           cB += lt[ROOT_T * N_TAGS + tg];
      if (t >= 1 && t < lenB)               cB += lt[tb1[t - 1] * N_TAGS + tg];
      if (t < lenB && t <= T_LEN - 2)       cB += fb1[t * N_TAGS + tg];
      if (t == lenB - 1)                    cB += lt[tg * N_TAGS + END_T];
      if (t == T_LEN - 1 && lenB == T_LEN)  cB += fb1[t * N_TAGS + tg];
    }
  }
  #pragma unroll
  for (int d = 1; d < 64; d <<= 1) { cA += __shfl_xor(cA, d); cB += __shfl_xor(cB, d); }
  if (lane == 0) { sred[0][wave] = cA; sred[1][wave] = cB; }

  // ---- partitions: logsumexp(alpha_128 + beta_128), wave 0, both chains ----
  float partA = 0.f, partB = 0.f;
  if (wave == 0) {
    const float xA0 = sA0 + bbs[0][2*lane], xA1 = sA1 + bbs[0][2*lane + 1];
    const float xB0 = sB0 + bbs[1][2*lane], xB1 = sB1 + bbs[1][2*lane + 1];
    float mwA = fmaxf(xA0, xA1), mwB = fmaxf(xB0, xB1);
    #pragma unroll
    for (int d = 1; d < 64; d <<= 1) {
      mwA = fmaxf(mwA, __shfl_xor(mwA, d));
      mwB = fmaxf(mwB, __shfl_xor(mwB, d));
    }
    float eA = __expf(xA0 - mwA) + __expf(xA1 - mwA);
    float eB = __expf(xB0 - mwB) + __expf(xB1 - mwB);
    #pragma unroll
    for (int d = 1; d < 64; d <<= 1) { eA += __shfl_xor(eA, d); eB += __shfl_xor(eB, d); }
    partA = mwA + __logf(eA);
    partB = mwB + __logf(eB);
  }
  __syncthreads();

  if (tid == 0) {
    per_batch[b0] = partA - (sred[0][0] + sred[0][1]);
    per_batch[b1] = partB - (sred[1][0] + sred[1][1]);
  }
}

// Deterministic final reduction: mean over 256 per-batch values.
__global__ __launch_bounds__(256) void crf_reduce_kernel(
    const float* __restrict__ per_batch, float* __restrict__ out)
{
  const int tid = threadIdx.x;
  float v = per_batch[tid] * (1.0f / BSZ);
  #pragma unroll
  for (int d = 1; d < 64; d <<= 1) v += __shfl_xor(v, d);
  __shared__ float r[4];
  if ((tid & 63) == 0) r[tid >> 6] = v;
  __syncthreads();
  if (tid == 0) out[0] = r[0] + r[1] + r[2] + r[3];
}

extern "C" void kernel_launch(void* const* d_in, const int* in_sizes, int n_in,
                              void* d_out, int out_size, void* d_ws, size_t ws_size,
                              hipStream_t stream) {
  (void)in_sizes; (void)n_in; (void)out_size; (void)ws_size;
  const float* feats = (const float*)d_in[0];
  const int*   tags  = (const int*)d_in[1];
  const int*   mask  = (const int*)d_in[2];
  const float* lt    = (const float*)d_in[3];
  float* per_batch = (float*)d_ws;   // 256 floats of scratch

  crf_fwd_kernel<<<BSZ / 2, 128, 0, stream>>>(feats, tags, mask, lt, per_batch);
  crf_reduce_kernel<<<1, 256, 0, stream>>>(per_batch, (float*)d_out);
}

// Round 9
// 78.727 us; speedup vs baseline: 2.6798x; 2.6798x over previous
//
#include <hip/hip_runtime.h>
#include <hip/hip_bf16.h>

#define N_TAGS 128
#define T_LEN  256
#define BSZ    256
#define ROOT_T 126
#define END_T  127

typedef _Float16 h2 __attribute__((ext_vector_type(2)));
typedef int   i32x4 __attribute__((ext_vector_type(4)));

static __device__ __forceinline__ h2 pkrtz(float a, float b) {
  return __builtin_bit_cast(h2, __builtin_amdgcn_cvt_pkrtz(a, b));
}
static __device__ __forceinline__ float rfl(float x) {
  return __int_as_float(__builtin_amdgcn_readfirstlane(__float_as_int(x)));
}
// Pull lane k's packed h2 to a wave-uniform (SGPR) value. k is a literal.
static __device__ __forceinline__ h2 rdl(h2 v, int k) {
  return __builtin_bit_cast(h2, __builtin_amdgcn_readlane(__builtin_bit_cast(int, v), k));
}
static __device__ __forceinline__ float fdot2(h2 a, h2 b, float c) {
#if __has_builtin(__builtin_amdgcn_fdot2)
  return __builtin_amdgcn_fdot2(a, b, c, false);
#else
  float d;
  asm("v_dot2_f32_f16 %0, %1, %2, %3" : "=v"(d) : "v"(a), "v"(b), "v"(c));
  return d;
#endif
}
static __device__ __forceinline__ float wave_max(float x) {
  #pragma unroll
  for (int d = 1; d < 64; d <<= 1) x = fmaxf(x, __shfl_xor(x, d));
  return x;
}

// LDS-free 128-length dual dot. The p-vector lives distributed in vp (lane k
// holds tags {2k,2k+1}); v_readlane broadcasts each h2 to all lanes as an
// SGPR operand of v_dot2_f32_f16 (VOP3P: 1 SGPR src is legal). No DS ops.
static __device__ __forceinline__ void dotRL(h2 vp,
                                             const h2 (&EA)[64], const h2 (&EB)[64],
                                             float& s0, float& s1) {
  float a0=0.f,a1=0.f,a2=0.f,a3=0.f, b0=0.f,b1=0.f,b2=0.f,b3=0.f;
  #pragma unroll
  for (int q = 0; q < 64; q += 4) {
    const h2 u0 = rdl(vp, q + 0);
    const h2 u1 = rdl(vp, q + 1);
    const h2 u2 = rdl(vp, q + 2);
    const h2 u3 = rdl(vp, q + 3);
    a0 = fdot2(u0, EA[q + 0], a0);  b0 = fdot2(u0, EB[q + 0], b0);
    a1 = fdot2(u1, EA[q + 1], a1);  b1 = fdot2(u1, EB[q + 1], b1);
    a2 = fdot2(u2, EA[q + 2], a2);  b2 = fdot2(u2, EB[q + 2], b2);
    a3 = fdot2(u3, EA[q + 3], a3);  b3 = fdot2(u3, EB[q + 3], b3);
  }
  s0 = (a0 + a1) + (a2 + a3);
  s1 = (b0 + b1) + (b2 + b3);
}

// One block per batch, 128 threads = 2 waves, ZERO LDS ops in the main loops.
// Wave 0 (fwd): lane l owns columns 2l,2l+1 of E=exp(lt) as f16 row-pairs.
// Wave 1 (bwd): lane l owns rows    2l,2l+1 of E as f16 col-pairs.
// p broadcast via v_readlane (SGPR), normalizer via readfirstlane (+2 guard).
__global__ void
__attribute__((amdgpu_flat_work_group_size(128, 128), amdgpu_waves_per_eu(1, 1)))
crf_fwd_kernel(
    const float* __restrict__ feats,   // [BSZ][T_LEN][N_TAGS]
    const int*   __restrict__ tags,    // [BSZ][T_LEN]
    const int*   __restrict__ mask,    // [BSZ][T_LEN]
    const float* __restrict__ lt,      // [N_TAGS][N_TAGS]
    float*       __restrict__ per_batch)
{
  const int b    = blockIdx.x;
  const int tid  = threadIdx.x;
  const int lane = tid & 63;
  const int wave = tid >> 6;

  __shared__ float stage[32 * 129];
  __shared__ float bb[N_TAGS];
  __shared__ float sred[2];

  const float* fb = feats + (size_t)b * T_LEN * N_TAGS;
  const int*   tb = tags  + b * T_LEN;

  // ---- sequence length (prefix mask), per-wave independent ----
  int len;
  {
    const i32x4 mv = ((const i32x4*)(mask + b * T_LEN))[lane];
    int v = mv.x + mv.y + mv.z + mv.w;
    #pragma unroll
    for (int d = 1; d < 64; d <<= 1) v += __shfl_xor(v, d);
    len = __builtin_amdgcn_readfirstlane(v);
  }

  // ---- build f16 register-resident E = exp(lt) ----
  // fwd lane l: EA[q]={E[2q][2l],E[2q+1][2l]}, EB same for col 2l+1.
  // bwd lane l: EA[q]={E[2l][2q],E[2l][2q+1]}, EB same for row 2l+1.
  h2 EA[64], EB[64];
  #pragma unroll
  for (int c = 0; c < 4; ++c) {
    __syncthreads();
    #pragma unroll
    for (int rr = 0; rr < 32; ++rr)
      stage[rr * 129 + tid] = __expf(lt[(c * 32 + rr) * N_TAGS + tid]);
    __syncthreads();
    if (wave == 0) {
      #pragma unroll
      for (int k = 0; k < 16; ++k) {
        h2 ea, eb;
        ea.x = (_Float16)stage[(2*k)   * 129 + 2*lane];
        ea.y = (_Float16)stage[(2*k+1) * 129 + 2*lane];
        eb.x = (_Float16)stage[(2*k)   * 129 + 2*lane + 1];
        eb.y = (_Float16)stage[(2*k+1) * 129 + 2*lane + 1];
        EA[c*16 + k] = ea;
        EB[c*16 + k] = eb;
      }
    } else if ((lane >> 4) == c) {        // rows 2l,2l+1 live in chunk c
      const int r0 = 2 * lane - 32 * c;
      #pragma unroll
      for (int q = 0; q < 64; ++q) {
        h2 ea, eb;
        ea.x = (_Float16)stage[r0       * 129 + 2*q];
        ea.y = (_Float16)stage[r0       * 129 + 2*q + 1];
        eb.x = (_Float16)stage[(r0 + 1) * 129 + 2*q];
        eb.y = (_Float16)stage[(r0 + 1) * 129 + 2*q + 1];
        EA[q] = ea;
        EB[q] = eb;
      }
    }
  }

  float st0, st1;

  if (wave == 0) {
    // ========== FORWARD: alpha, steps t=1..128 (active iff t<len) ==========
    {
      const float2 f0 = ((const float2*)fb)[lane];
      st0 = lt[ROOT_T * N_TAGS + 2*lane]     + f0.x;
      st1 = lt[ROOT_T * N_TAGS + 2*lane + 1] + f0.y;
    }
    float2 fa = ((const float2*)(fb + 1 * N_TAGS))[lane];
    float2 fc = ((const float2*)(fb + 2 * N_TAGS))[lane];
    float2 fd = ((const float2*)(fb + 3 * N_TAGS))[lane];
    float m_cur = rfl(st0) + 2.0f;
    h2 vp = pkrtz(__expf(st0 - m_cur), __expf(st1 - m_cur));

    #pragma unroll 1
    for (int t = 1; t <= 128; ++t) {
      float s0, s1;
      dotRL(vp, EA, EB, s0, s1);
      const float nf0 = m_cur + __logf(s0) + fa.x;
      const float nf1 = m_cur + __logf(s1) + fa.y;
      const bool act = (t < len);
      st0 = act ? nf0 : st0;  st1 = act ? nf1 : st1;
      fa = fc;  fc = fd;
      fd = ((const float2*)(fb + (t + 3) * N_TAGS))[lane];   // rows 4..131
      const float m = rfl(st0) + 2.0f;
      vp = pkrtz(__expf(st0 - m), __expf(st1 - m));
      m_cur = m;
    }
    // st = alpha_128 (frozen at alpha_{len-1} for len<=128)
  } else {
    // ========== BACKWARD: beta, step k uses f[255-k];
    //            active iff 256-len <= k <= 126; ends at beta_128 ==========
    st0 = lt[(2*lane)     * N_TAGS + END_T];   // beta_{len-1}
    st1 = lt[(2*lane + 1) * N_TAGS + END_T];
    float2 fw = ((const float2*)(fb + 255 * N_TAGS))[lane];  // f255
    float2 fa = ((const float2*)(fb + 254 * N_TAGS))[lane];  // f254
    float2 fc = ((const float2*)(fb + 253 * N_TAGS))[lane];
    float2 fd = ((const float2*)(fb + 252 * N_TAGS))[lane];
    const float y0i = st0 + fw.x, y1i = st1 + fw.y;
    float m_cur = rfl(y0i) + 2.0f;
    h2 vp = pkrtz(__expf(y0i - m_cur), __expf(y1i - m_cur));

    const int kmin = 256 - len;              // first active step
    #pragma unroll 1
    for (int k = 0; k <= 127; ++k) {
      float s0, s1;
      dotRL(vp, EA, EB, s0, s1);
      const float nb0 = m_cur + __logf(s0);
      const float nb1 = m_cur + __logf(s1);
      const bool act = (k >= kmin) && (k <= 126);
      st0 = act ? nb0 : st0;  st1 = act ? nb1 : st1;
      const float w0 = fa.x, w1 = fa.y;      // f[254-k]
      fa = fc;  fc = fd;
      fd = ((const float2*)(fb + (251 - k) * N_TAGS))[lane]; // rows 251..124
      const float y0 = st0 + w0, y1 = st1 + w1;
      const float m = rfl(y0) + 2.0f;
      vp = pkrtz(__expf(y0 - m), __expf(y1 - m));
      m_cur = m;
    }
    // st = beta_128
    bb[2*lane]     = st0;
    bb[2*lane + 1] = st1;
  }
  __syncthreads();

  // ---- gold-path score: 2 timesteps per thread ----
  float c = 0.f;
  #pragma unroll
  for (int q = 0; q < 2; ++q) {
    const int t  = tid + q * N_TAGS;
    const int tg = tb[t];
    if (t == 0)                           c += lt[ROOT_T * N_TAGS + tg];
    if (t >= 1 && t < len)                c += lt[tb[t - 1] * N_TAGS + tg];
    if (t < len && t <= T_LEN - 2)        c += fb[t * N_TAGS + tg];
    if (t == len - 1)                     c += lt[tg * N_TAGS + END_T];
    if (t == T_LEN - 1 && len == T_LEN)   c += fb[t * N_TAGS + tg];
  }
  #pragma unroll
  for (int d = 1; d < 64; d <<= 1) c += __shfl_xor(c, d);
  if (lane == 0) sred[wave] = c;

  // ---- partition: logsumexp(alpha_128 + beta_128), wave 0 ----
  float part = 0.f;
  if (wave == 0) {
    const float x0 = st0 + bb[2*lane];
    const float x1 = st1 + bb[2*lane + 1];
    const float mw = wave_max(fmaxf(x0, x1));
    float e = __expf(x0 - mw) + __expf(x1 - mw);
    #pragma unroll
    for (int d = 1; d < 64; d <<= 1) e += __shfl_xor(e, d);
    part = mw + __logf(e);
  }
  __syncthreads();

  if (tid == 0) per_batch[b] = part - (sred[0] + sred[1]);
}

// Deterministic final reduction: mean over 256 per-batch values.
__global__ __launch_bounds__(256) void crf_reduce_kernel(
    const float* __restrict__ per_batch, float* __restrict__ out)
{
  const int tid = threadIdx.x;
  float v = per_batch[tid] * (1.0f / BSZ);
  #pragma unroll
  for (int d = 1; d < 64; d <<= 1) v += __shfl_xor(v, d);
  __shared__ float r[4];
  if ((tid & 63) == 0) r[tid >> 6] = v;
  __syncthreads();
  if (tid == 0) out[0] = r[0] + r[1] + r[2] + r[3];
}

extern "C" void kernel_launch(void* const* d_in, const int* in_sizes, int n_in,
                              void* d_out, int out_size, void* d_ws, size_t ws_size,
                              hipStream_t stream) {
  (void)in_sizes; (void)n_in; (void)out_size; (void)ws_size;
  const float* feats = (const float*)d_in[0];
  const int*   tags  = (const int*)d_in[1];
  const int*   mask  = (const int*)d_in[2];
  const float* lt    = (const float*)d_in[3];
  float* per_batch = (float*)d_ws;   // 256 floats of scratch

  crf_fwd_kernel<<<BSZ, 128, 0, stream>>>(feats, tags, mask, lt, per_batch);
  crf_reduce_kernel<<<1, 256, 0, stream>>>(per_batch, (float*)d_out);
}

// Round 10
// 76.204 us; speedup vs baseline: 2.7685x; 1.0331x over previous
//
#include <hip/hip_runtime.h>
#include <hip/hip_bf16.h>

#define N_TAGS 128
#define T_LEN  256
#define BSZ    256
#define ROOT_T 126
#define END_T  127

typedef _Float16 h2 __attribute__((ext_vector_type(2)));
typedef int   i32x4 __attribute__((ext_vector_type(4)));

static __device__ __forceinline__ h2 pkrtz(float a, float b) {
  return __builtin_bit_cast(h2, __builtin_amdgcn_cvt_pkrtz(a, b));
}
static __device__ __forceinline__ float rfl(float x) {
  return __int_as_float(__builtin_amdgcn_readfirstlane(__float_as_int(x)));
}
// Pull lane k's packed h2 to a wave-uniform (SGPR) value. k is a literal.
static __device__ __forceinline__ h2 rdl(h2 v, int k) {
  return __builtin_bit_cast(h2, __builtin_amdgcn_readlane(__builtin_bit_cast(int, v), k));
}
static __device__ __forceinline__ float fdot2(h2 a, h2 b, float c) {
#if __has_builtin(__builtin_amdgcn_fdot2)
  return __builtin_amdgcn_fdot2(a, b, c, false);
#else
  float d;
  asm("v_dot2_f32_f16 %0, %1, %2, %3" : "=v"(d) : "v"(a), "v"(b), "v"(c));
  return d;
#endif
}
static __device__ __forceinline__ float wave_max(float x) {
  #pragma unroll
  for (int d = 1; d < 64; d <<= 1) x = fmaxf(x, __shfl_xor(x, d));
  return x;
}

// LDS-free 128-length dual dot. The p-vector lives distributed in vp (lane k
// holds tags {2k,2k+1}); v_readlane broadcasts each h2 to all lanes as an
// SGPR operand of v_dot2_f32_f16 (VOP3P: 1 SGPR src is legal). No DS ops.
static __device__ __forceinline__ void dotRL(h2 vp,
                                             const h2 (&EA)[64], const h2 (&EB)[64],
                                             float& s0, float& s1) {
  float a0=0.f,a1=0.f,a2=0.f,a3=0.f, b0=0.f,b1=0.f,b2=0.f,b3=0.f;
  #pragma unroll
  for (int q = 0; q < 64; q += 4) {
    const h2 u0 = rdl(vp, q + 0);
    const h2 u1 = rdl(vp, q + 1);
    const h2 u2 = rdl(vp, q + 2);
    const h2 u3 = rdl(vp, q + 3);
    a0 = fdot2(u0, EA[q + 0], a0);  b0 = fdot2(u0, EB[q + 0], b0);
    a1 = fdot2(u1, EA[q + 1], a1);  b1 = fdot2(u1, EB[q + 1], b1);
    a2 = fdot2(u2, EA[q + 2], a2);  b2 = fdot2(u2, EB[q + 2], b2);
    a3 = fdot2(u3, EA[q + 3], a3);  b3 = fdot2(u3, EB[q + 3], b3);
  }
  s0 = (a0 + a1) + (a2 + a3);
  s1 = (b0 + b1) + (b2 + b3);
}

// One block per batch, 128 threads = 2 waves, ZERO LDS ops in the main loops.
// Wave 0 (fwd): lane l owns columns 2l,2l+1 of E=exp(lt) as f16 row-pairs.
// Wave 1 (bwd): lane l owns rows    2l,2l+1 of E as f16 col-pairs.
// p broadcast via v_readlane (SGPR), normalizer via readfirstlane (+2 guard).
// Feat prefetch: depth-4 rotating buffer with LITERAL indices (unroll 4) so
// loads stay 4 bodies ahead of use -> compiler emits vmcnt(3)-style waits
// instead of the vmcnt(0)-per-step stall the old fa=fc;fc=fd shift forced.
__global__ void
__attribute__((amdgpu_flat_work_group_size(128, 128), amdgpu_waves_per_eu(1, 1)))
crf_fwd_kernel(
    const float* __restrict__ feats,   // [BSZ][T_LEN][N_TAGS]
    const int*   __restrict__ tags,    // [BSZ][T_LEN]
    const int*   __restrict__ mask,    // [BSZ][T_LEN]
    const float* __restrict__ lt,      // [N_TAGS][N_TAGS]
    float*       __restrict__ per_batch)
{
  const int b    = blockIdx.x;
  const int tid  = threadIdx.x;
  const int lane = tid & 63;
  const int wave = tid >> 6;

  __shared__ float stage[32 * 129];
  __shared__ float bb[N_TAGS];
  __shared__ float sred[2];

  const float* fb = feats + (size_t)b * T_LEN * N_TAGS;
  const int*   tb = tags  + b * T_LEN;

  // ---- sequence length (prefix mask), per-wave independent ----
  int len;
  {
    const i32x4 mv = ((const i32x4*)(mask + b * T_LEN))[lane];
    int v = mv.x + mv.y + mv.z + mv.w;
    #pragma unroll
    for (int d = 1; d < 64; d <<= 1) v += __shfl_xor(v, d);
    len = __builtin_amdgcn_readfirstlane(v);
  }

  // ---- build f16 register-resident E = exp(lt) ----
  // fwd lane l: EA[q]={E[2q][2l],E[2q+1][2l]}, EB same for col 2l+1.
  // bwd lane l: EA[q]={E[2l][2q],E[2l][2q+1]}, EB same for row 2l+1.
  h2 EA[64], EB[64];
  #pragma unroll
  for (int c = 0; c < 4; ++c) {
    __syncthreads();
    #pragma unroll
    for (int rr = 0; rr < 32; ++rr)
      stage[rr * 129 + tid] = __expf(lt[(c * 32 + rr) * N_TAGS + tid]);
    __syncthreads();
    if (wave == 0) {
      #pragma unroll
      for (int k = 0; k < 16; ++k) {
        h2 ea, eb;
        ea.x = (_Float16)stage[(2*k)   * 129 + 2*lane];
        ea.y = (_Float16)stage[(2*k+1) * 129 + 2*lane];
        eb.x = (_Float16)stage[(2*k)   * 129 + 2*lane + 1];
        eb.y = (_Float16)stage[(2*k+1) * 129 + 2*lane + 1];
        EA[c*16 + k] = ea;
        EB[c*16 + k] = eb;
      }
    } else if ((lane >> 4) == c) {        // rows 2l,2l+1 live in chunk c
      const int r0 = 2 * lane - 32 * c;
      #pragma unroll
      for (int q = 0; q < 64; ++q) {
        h2 ea, eb;
        ea.x = (_Float16)stage[r0       * 129 + 2*q];
        ea.y = (_Float16)stage[r0       * 129 + 2*q + 1];
        eb.x = (_Float16)stage[(r0 + 1) * 129 + 2*q];
        eb.y = (_Float16)stage[(r0 + 1) * 129 + 2*q + 1];
        EA[q] = ea;
        EB[q] = eb;
      }
    }
  }

  float st0, st1;

  if (wave == 0) {
    // ========== FORWARD: alpha, steps t=1..128 (active iff t<len) ==========
    {
      const float2 f0 = ((const float2*)fb)[lane];
      st0 = lt[ROOT_T * N_TAGS + 2*lane]     + f0.x;
      st1 = lt[ROOT_T * N_TAGS + 2*lane + 1] + f0.y;
    }
    // depth-4 rotating prefetch buffer: buf[t&3] holds feat row t
    float2 buf[4];
    buf[1] = ((const float2*)(fb + 1 * N_TAGS))[lane];
    buf[2] = ((const float2*)(fb + 2 * N_TAGS))[lane];
    buf[3] = ((const float2*)(fb + 3 * N_TAGS))[lane];
    buf[0] = ((const float2*)(fb + 4 * N_TAGS))[lane];
    float m_cur = rfl(st0) + 2.0f;
    h2 vp = pkrtz(__expf(st0 - m_cur), __expf(st1 - m_cur));

    #pragma unroll 4
    for (int t = 1; t <= 128; ++t) {
      float s0, s1;
      dotRL(vp, EA, EB, s0, s1);
      const float2 fa = buf[t & 3];                           // row t
      buf[t & 3] = ((const float2*)(fb + (t + 4) * N_TAGS))[lane];  // row t+4
      const float nf0 = m_cur + __logf(s0) + fa.x;
      const float nf1 = m_cur + __logf(s1) + fa.y;
      const bool act = (t < len);
      st0 = act ? nf0 : st0;  st1 = act ? nf1 : st1;
      const float m = rfl(st0) + 2.0f;
      vp = pkrtz(__expf(st0 - m), __expf(st1 - m));
      m_cur = m;
    }
    // st = alpha_128 (frozen at alpha_{len-1} for len<=128)
  } else {
    // ========== BACKWARD: beta, step k uses f[255-k] read / f[254-k] write;
    //            active iff 256-len <= k <= 126; ends at beta_128 ==========
    st0 = lt[(2*lane)     * N_TAGS + END_T];   // beta_{len-1}
    st1 = lt[(2*lane + 1) * N_TAGS + END_T];
    const float2 fw = ((const float2*)(fb + 255 * N_TAGS))[lane];  // f255
    // depth-4 rotating prefetch buffer: buf[k&3] holds feat row 254-k
    float2 buf[4];
    buf[0] = ((const float2*)(fb + 254 * N_TAGS))[lane];
    buf[1] = ((const float2*)(fb + 253 * N_TAGS))[lane];
    buf[2] = ((const float2*)(fb + 252 * N_TAGS))[lane];
    buf[3] = ((const float2*)(fb + 251 * N_TAGS))[lane];
    const float y0i = st0 + fw.x, y1i = st1 + fw.y;
    float m_cur = rfl(y0i) + 2.0f;
    h2 vp = pkrtz(__expf(y0i - m_cur), __expf(y1i - m_cur));

    const int kmin = 256 - len;              // first active step
    #pragma unroll 4
    for (int k = 0; k <= 127; ++k) {
      float s0, s1;
      dotRL(vp, EA, EB, s0, s1);
      const float nb0 = m_cur + __logf(s0);
      const float nb1 = m_cur + __logf(s1);
      const bool act = (k >= kmin) && (k <= 126);
      st0 = act ? nb0 : st0;  st1 = act ? nb1 : st1;
      const float2 fa = buf[k & 3];                           // row 254-k
      buf[k & 3] = ((const float2*)(fb + (250 - k) * N_TAGS))[lane]; // row 250-k
      const float y0 = st0 + fa.x, y1 = st1 + fa.y;
      const float m = rfl(y0) + 2.0f;
      vp = pkrtz(__expf(y0 - m), __expf(y1 - m));
      m_cur = m;
    }
    // st = beta_128
    bb[2*lane]     = st0;
    bb[2*lane + 1] = st1;
  }
  __syncthreads();

  // ---- gold-path score: 2 timesteps per thread ----
  float c = 0.f;
  #pragma unroll
  for (int q = 0; q < 2; ++q) {
    const int t  = tid + q * N_TAGS;
    const int tg = tb[t];
    if (t == 0)                           c += lt[ROOT_T * N_TAGS + tg];
    if (t >= 1 && t < len)                c += lt[tb[t - 1] * N_TAGS + tg];
    if (t < len && t <= T_LEN - 2)        c += fb[t * N_TAGS + tg];
    if (t == len - 1)                     c += lt[tg * N_TAGS + END_T];
    if (t == T_LEN - 1 && len == T_LEN)   c += fb[t * N_TAGS + tg];
  }
  #pragma unroll
  for (int d = 1; d < 64; d <<= 1) c += __shfl_xor(c, d);
  if (lane == 0) sred[wave] = c;

  // ---- partition: logsumexp(alpha_128 + beta_128), wave 0 ----
  float part = 0.f;
  if (wave == 0) {
    const float x0 = st0 + bb[2*lane];
    const float x1 = st1 + bb[2*lane + 1];
    const float mw = wave_max(fmaxf(x0, x1));
    float e = __expf(x0 - mw) + __expf(x1 - mw);
    #pragma unroll
    for (int d = 1; d < 64; d <<= 1) e += __shfl_xor(e, d);
    part = mw + __logf(e);
  }
  __syncthreads();

  if (tid == 0) per_batch[b] = part - (sred[0] + sred[1]);
}

// Deterministic final reduction: mean over 256 per-batch values.
__global__ __launch_bounds__(256) void crf_reduce_kernel(
    const float* __restrict__ per_batch, float* __restrict__ out)
{
  const int tid = threadIdx.x;
  float v = per_batch[tid] * (1.0f / BSZ);
  #pragma unroll
  for (int d = 1; d < 64; d <<= 1) v += __shfl_xor(v, d);
  __shared__ float r[4];
  if ((tid & 63) == 0) r[tid >> 6] = v;
  __syncthreads();
  if (tid == 0) out[0] = r[0] + r[1] + r[2] + r[3];
}

extern "C" void kernel_launch(void* const* d_in, const int* in_sizes, int n_in,
                              void* d_out, int out_size, void* d_ws, size_t ws_size,
                              hipStream_t stream) {
  (void)in_sizes; (void)n_in; (void)out_size; (void)ws_size;
  const float* feats = (const float*)d_in[0];
  const int*   tags  = (const int*)d_in[1];
  const int*   mask  = (const int*)d_in[2];
  const float* lt    = (const float*)d_in[3];
  float* per_batch = (float*)d_ws;   // 256 floats of scratch

  crf_fwd_kernel<<<BSZ, 128, 0, stream>>>(feats, tags, mask, lt, per_batch);
  crf_reduce_kernel<<<1, 256, 0, stream>>>(per_batch, (float*)d_out);
}